// Round 5
// baseline (465.688 us; speedup 1.0000x reference)
//
#include <hip/hip_runtime.h>
#include <math.h>

#define IN_CH 128
#define OUT_CH 16
#define B 256
#define CH 16384          // edges per sort chunk
#define LSH 6             // leaf = node >> 6  (64 nodes per leaf)
#define LNODES 64
#define PAD 17            // LDS acc row stride (bank-conflict pad)
#define MAXNL 1024
#define MAXG 256

// ================= main path: counting-sort by leaf, LDS-accumulated hops =================

// --- per-chunk leaf histogram (no global atomics) ---
__global__ void k_hist(const int* __restrict__ col, unsigned* __restrict__ bh, int E, int NL) {
    __shared__ unsigned hc[MAXNL];
    for (int i = threadIdx.x; i < NL; i += B) hc[i] = 0u;
    __syncthreads();
    int base = blockIdx.x * CH;
    int end = base + CH < E ? base + CH : E;
    for (int e = base + threadIdx.x; e < end; e += B)
        atomicAdd(&hc[col[e] >> LSH], 1u);
    __syncthreads();
    unsigned* out = bh + (size_t)blockIdx.x * NL;
    for (int i = threadIdx.x; i < NL; i += B) out[i] = hc[i];
}

// --- per-leaf exclusive scan over chunks; totals out (one block per leaf) ---
__global__ void k_colscan(unsigned* __restrict__ bh, unsigned* __restrict__ tot, int G, int NL) {
    int j = blockIdx.x;
    __shared__ unsigned s[B];
    int tid = threadIdx.x;
    unsigned v = (tid < G) ? bh[(size_t)tid * NL + j] : 0u;
    s[tid] = v;
    __syncthreads();
    for (int off = 1; off < B; off <<= 1) {
        unsigned add = (tid >= off) ? s[tid - off] : 0u;
        __syncthreads();
        s[tid] += add;
        __syncthreads();
    }
    unsigned excl = s[tid] - v;
    if (tid < G) bh[(size_t)tid * NL + j] = excl;
    if (tid == B - 1) tot[j] = s[tid];
}

// --- exclusive scan of leaf totals -> ptr[NL+1] (single block) ---
__global__ void k_scanptr(const unsigned* __restrict__ tot, unsigned* __restrict__ ptr, int NL) {
    __shared__ unsigned sums[B];
    int tid = threadIdx.x;
    unsigned v[4];
    int base = tid * 4;
    unsigned loc = 0;
#pragma unroll
    for (int q = 0; q < 4; ++q) {
        int i = base + q;
        v[q] = (i < NL) ? tot[i] : 0u;
        loc += v[q];
    }
    sums[tid] = loc;
    __syncthreads();
    for (int off = 1; off < B; off <<= 1) {
        unsigned add = (tid >= off) ? sums[tid - off] : 0u;
        __syncthreads();
        sums[tid] += add;
        __syncthreads();
    }
    unsigned run = sums[tid] - loc;  // exclusive
#pragma unroll
    for (int q = 0; q < 4; ++q) {
        int i = base + q;
        if (i < NL) ptr[i] = run;
        run += v[q];
    }
    if (tid == B - 1) ptr[NL] = run;
}

// --- placement: scatter edges into leaf-grouped arrays (LDS position counters) ---
__global__ void k_place(const int* __restrict__ row, const int* __restrict__ col,
                        const float* __restrict__ ew, const unsigned* __restrict__ bh,
                        const unsigned* __restrict__ ptr,
                        unsigned short* __restrict__ srow, unsigned char* __restrict__ scl,
                        float* __restrict__ sew, int E, int NL) {
    __shared__ unsigned ctr[MAXNL];
    const unsigned* myb = bh + (size_t)blockIdx.x * NL;
    for (int i = threadIdx.x; i < NL; i += B) ctr[i] = ptr[i] + myb[i];
    __syncthreads();
    int base = blockIdx.x * CH;
    int end = base + CH < E ? base + CH : E;
    for (int e = base + threadIdx.x; e < end; e += B) {
        int c = col[e];
        unsigned pos = atomicAdd(&ctr[c >> LSH], 1u);
        srow[pos] = (unsigned short)row[e];
        scl[pos]  = (unsigned char)(c & (LNODES - 1));
        sew[pos]  = ew[e];
    }
}

// --- per-leaf degree -> dinv (LDS accumulation) ---
__global__ void k_leafdeg(const unsigned char* __restrict__ scl, const float* __restrict__ sew,
                          const unsigned* __restrict__ ptr, float* __restrict__ dinv, int N) {
    __shared__ float dacc[LNODES];
    int leaf = blockIdx.x;
    if (threadIdx.x < LNODES) dacc[threadIdx.x] = 0.f;
    __syncthreads();
    int seg = (int)ptr[leaf], end = (int)ptr[leaf + 1];
    for (int j = seg + threadIdx.x; j < end; j += B)
        atomicAdd(&dacc[scl[j]], sew[j]);
    __syncthreads();
    if (threadIdx.x < LNODES) {
        int n = leaf * LNODES + threadIdx.x;
        if (n < N) dinv[n] = rsqrtf(1.0f + dacc[threadIdx.x]);
    }
}

// --- projection: h0 = x @ W^T ---
__global__ void k_proj(const float* __restrict__ x, const float* __restrict__ W,
                       float* __restrict__ y, int N) {
    __shared__ float sW[OUT_CH * (IN_CH + 1)];
    for (int i = threadIdx.x; i < OUT_CH * IN_CH; i += blockDim.x) {
        int o = i >> 7, k = i & 127;
        sW[o * (IN_CH + 1) + k] = W[i];
    }
    __syncthreads();
    int t = threadIdx.x;
    int n = blockIdx.x * 16 + (t >> 4);
    int o = t & 15;
    if (n >= N) return;
    const float* xr = x + (size_t)n * IN_CH;
    const float* wr = sW + o * (IN_CH + 1);
    float acc = 0.0f;
#pragma unroll
    for (int k = 0; k < IN_CH; k += 4) {
        float4 xv = *reinterpret_cast<const float4*>(xr + k);
        acc += xv.x * wr[k] + xv.y * wr[k + 1] + xv.z * wr[k + 2] + xv.w * wr[k + 3];
    }
    y[(size_t)n * OUT_CH + o] = acc;
}

// --- hop: per-leaf gather + LDS accumulate; FINAL fuses log_softmax ---
template <bool FINAL>
__global__ void __launch_bounds__(B)
k_hop(const unsigned short* __restrict__ srow, const unsigned char* __restrict__ scl,
      const float* __restrict__ sew, const unsigned* __restrict__ ptr,
      const float* __restrict__ dinv, const float* __restrict__ hin,
      float* __restrict__ hout, int N) {
    __shared__ float acc[LNODES * PAD];
    __shared__ float dloc[LNODES];
    int tid = threadIdx.x;
    int leaf = blockIdx.x;
    for (int i = tid; i < LNODES * PAD; i += B) acc[i] = 0.f;
    if (tid < LNODES) {
        int n = leaf * LNODES + tid;
        dloc[tid] = (n < N) ? dinv[n] : 0.f;
    }
    __syncthreads();
    int seg = (int)ptr[leaf];
    int cnt = (int)ptr[leaf + 1] - seg;
    int ch = tid & 15;
    for (int j = tid; j < cnt * OUT_CH; j += B) {
        int e = seg + (j >> 4);
        int c6 = scl[e];
        int r = srow[e];
        float nv = dinv[r] * sew[e] * dloc[c6];
        atomicAdd(&acc[c6 * PAD + ch], nv * hin[(size_t)r * OUT_CH + ch]);
    }
    __syncthreads();
    if (!FINAL) {
        for (int i = tid; i < LNODES * OUT_CH; i += B) {
            int n = leaf * LNODES + (i >> 4);
            if (n < N) {
                float d = dloc[i >> 4];
                hout[(size_t)n * OUT_CH + (i & 15)] =
                    d * d * hin[(size_t)n * OUT_CH + (i & 15)] + acc[(i >> 4) * PAD + (i & 15)];
            }
        }
    } else {
        if (tid < LNODES) {
            int n = leaf * LNODES + tid;
            if (n < N) {
                float d = dloc[tid], v[OUT_CH];
                float m = -1e30f;
#pragma unroll
                for (int c = 0; c < OUT_CH; ++c) {
                    v[c] = d * d * hin[(size_t)n * OUT_CH + c] + acc[tid * PAD + c];
                    m = fmaxf(m, v[c]);
                }
                float s = 0.f;
#pragma unroll
                for (int c = 0; c < OUT_CH; ++c) s += expf(v[c] - m);
                float lse = m + logf(s);
#pragma unroll
                for (int c = 0; c < OUT_CH; ++c)
                    hout[(size_t)n * OUT_CH + c] = v[c] - lse;
            }
        }
    }
}

// ================= fallback path (proven r2 structure, device atomics) =================

__global__ void fb_deginit(float* deg, int N) {
    int i = blockIdx.x * blockDim.x + threadIdx.x;
    if (i < N) deg[i] = 1.0f;
}
__global__ void fb_deg(const int* __restrict__ col, const float* __restrict__ ew,
                       float* deg, int E) {
    int e = blockIdx.x * blockDim.x + threadIdx.x;
    if (e < E) atomicAdd(&deg[col[e]], ew[e]);
}
__global__ void fb_dinv(const float* __restrict__ deg, float* dinv, int N) {
    int i = blockIdx.x * blockDim.x + threadIdx.x;
    if (i < N) dinv[i] = rsqrtf(deg[i]);
}
__global__ void fb_selfinit(const float* __restrict__ hin, const float* __restrict__ dinv,
                            float* __restrict__ hout, int N) {
    int idx = blockIdx.x * blockDim.x + threadIdx.x;
    if (idx < N * OUT_CH) {
        float d = dinv[idx >> 4];
        hout[idx] = d * d * hin[idx];
    }
}
__global__ void fb_scat(const int* __restrict__ row, const int* __restrict__ col,
                        const float* __restrict__ ew, const float* __restrict__ dinv,
                        const float* __restrict__ hin, float* __restrict__ hout, int E) {
    long long idx = (long long)blockIdx.x * blockDim.x + threadIdx.x;
    int e = (int)(idx >> 4);
    int c = (int)(idx & 15);
    if (e >= E) return;
    int r = row[e], cl = col[e];
    float nv = dinv[r] * ew[e] * dinv[cl];
    atomicAdd(&hout[(size_t)cl * OUT_CH + c], nv * hin[(size_t)r * OUT_CH + c]);
}
__global__ void fb_lsm(const float* __restrict__ h, float* __restrict__ out, int N) {
    int n = blockIdx.x * blockDim.x + threadIdx.x;
    if (n >= N) return;
    const float* hr = h + (size_t)n * OUT_CH;
    float v[OUT_CH];
#pragma unroll
    for (int i = 0; i < OUT_CH; i++) v[i] = hr[i];
    float m = v[0];
#pragma unroll
    for (int i = 1; i < OUT_CH; i++) m = fmaxf(m, v[i]);
    float s = 0.0f;
#pragma unroll
    for (int i = 0; i < OUT_CH; i++) s += expf(v[i] - m);
    float lse = m + logf(s);
    float* orow = out + (size_t)n * OUT_CH;
#pragma unroll
    for (int i = 0; i < OUT_CH; i++) orow[i] = v[i] - lse;
}

// ================= launch =================

extern "C" void kernel_launch(void* const* d_in, const int* in_sizes, int n_in,
                              void* d_out, int out_size, void* d_ws, size_t ws_size,
                              hipStream_t stream) {
    const float* x  = (const float*)d_in[0];
    const float* W  = (const float*)d_in[1];
    const float* ew = (const float*)d_in[2];
    const int*   ei = (const int*)d_in[3];  // harness pushes int64 as int32

    int N = in_sizes[0] / IN_CH;
    int E = in_sizes[2];
    const int* row = ei;       // source
    const int* col = ei + E;   // target

    auto al = [](size_t v) { return (v + 255) & ~(size_t)255; };
    size_t N16 = (size_t)N * OUT_CH;

    int NL = (N + LNODES - 1) >> LSH;
    int G  = (E + CH - 1) / CH;

    size_t o_bh   = 0;
    size_t o_tot  = o_bh   + al((size_t)G * NL * 4);
    size_t o_ptr  = o_tot  + al((size_t)NL * 4);
    size_t o_srow = o_ptr  + al((size_t)(NL + 1) * 4);
    size_t o_scl  = o_srow + al((size_t)E * 2);
    size_t o_sew  = o_scl  + al((size_t)E);
    size_t o_dinv = o_sew  + al((size_t)E * 4);
    size_t o_h0   = o_dinv + al((size_t)N * 4);
    size_t o_h1   = o_h0   + al(N16 * 4);
    size_t need   = o_h1   + al(N16 * 4);

    char* ws = (char*)d_ws;

    if (NL <= MAXNL && G <= MAXG && need <= ws_size) {
        // ---- main path ----
        unsigned*       bh   = (unsigned*)(ws + o_bh);
        unsigned*       tot  = (unsigned*)(ws + o_tot);
        unsigned*       ptr  = (unsigned*)(ws + o_ptr);
        unsigned short* srow = (unsigned short*)(ws + o_srow);
        unsigned char*  scl  = (unsigned char*)(ws + o_scl);
        float*          sew  = (float*)(ws + o_sew);
        float*          dinv = (float*)(ws + o_dinv);
        float*          h0   = (float*)(ws + o_h0);
        float*          h1   = (float*)(ws + o_h1);

        k_hist   <<<G,  B, 0, stream>>>(col, bh, E, NL);
        k_colscan<<<NL, B, 0, stream>>>(bh, tot, G, NL);
        k_scanptr<<<1,  B, 0, stream>>>(tot, ptr, NL);
        k_place  <<<G,  B, 0, stream>>>(row, col, ew, bh, ptr, srow, scl, sew, E, NL);
        k_leafdeg<<<NL, B, 0, stream>>>(scl, sew, ptr, dinv, N);
        k_proj   <<<(N + 15) / 16, B, 0, stream>>>(x, W, h0, N);
        k_hop<false><<<NL, B, 0, stream>>>(srow, scl, sew, ptr, dinv, h0, h1, N);
        k_hop<true ><<<NL, B, 0, stream>>>(srow, scl, sew, ptr, dinv, h1, (float*)d_out, N);
    } else {
        // ---- fallback (r2-style, ~6.8 MB ws) ----
        size_t f_deg  = 0;
        size_t f_dinv = f_deg  + al((size_t)N * 4);
        size_t f_h0   = f_dinv + al((size_t)N * 4);
        size_t f_h1   = f_h0   + al(N16 * 4);
        float* deg  = (float*)(ws + f_deg);
        float* dinv = (float*)(ws + f_dinv);
        float* h0   = (float*)(ws + f_h0);
        float* h1   = (float*)(ws + f_h1);

        int gN   = (N + B - 1) / B;
        int gE   = (E + B - 1) / B;
        int gN16 = (N * OUT_CH + B - 1) / B;
        long long scat = (long long)E * OUT_CH;
        int gScat = (int)((scat + B - 1) / B);

        fb_deginit<<<gN, B, 0, stream>>>(deg, N);
        fb_deg<<<gE, B, 0, stream>>>(col, ew, deg, E);
        fb_dinv<<<gN, B, 0, stream>>>(deg, dinv, N);
        k_proj<<<(N + 15) / 16, B, 0, stream>>>(x, W, h0, N);
        float* hin = h0; float* hout = h1;
        for (int k = 0; k < 2; k++) {
            fb_selfinit<<<gN16, B, 0, stream>>>(hin, dinv, hout, N);
            fb_scat<<<gScat, B, 0, stream>>>(row, col, ew, dinv, hin, hout, E);
            float* t = hin; hin = hout; hout = t;
        }
        fb_lsm<<<gN, B, 0, stream>>>(hin, (float*)d_out, N);
    }
}